// Round 1
// baseline (541.657 us; speedup 1.0000x reference)
//
#include <hip/hip_runtime.h>

#define SEQ 4096
#define DK  128
#define ROW (SEQ * DK)          // elements per (s,d) plane = 524288
#define ROW4 (ROW / 4)          // float4 elements per plane = 131072

// ---------------------------------------------------------------------------
// Kernel A: extract the diagonal of R into diagT laid out [s][d] so it
// matches x's innermost layout.  diagT[s*DK + d] = R[(d*DK + d)*SEQ + s].
// Tiny (2 MiB), runs in a few microseconds; coalesced writes, strided reads
// (total unique data is only the 2 MiB of diagonal cache lines).
// ---------------------------------------------------------------------------
__global__ void extract_diag_kernel(const float* __restrict__ R,
                                    float* __restrict__ diagT) {
    int idx = blockIdx.x * blockDim.x + threadIdx.x;   // 0 .. ROW-1
    if (idx < ROW) {
        int d = idx & (DK - 1);
        int s = idx >> 7;                              // idx / DK
        diagT[idx] = R[(size_t)(d * DK + d) * SEQ + s];
    }
}

// ---------------------------------------------------------------------------
// Kernel B: out4[i] = x4[i] * diagT4[i mod ROW4].  ROW4 is a power of two so
// the mod is a mask.  16 B/lane fully-coalesced loads and stores; diagT
// (2 MiB) is L2-resident.
// ---------------------------------------------------------------------------
__global__ void rope_scale_kernel(const float4* __restrict__ x,
                                  const float4* __restrict__ diagT,
                                  float4* __restrict__ out, int n4) {
    int i = blockIdx.x * blockDim.x + threadIdx.x;
    if (i < n4) {
        float4 xv = x[i];
        float4 dv = diagT[i & (ROW4 - 1)];
        out[i] = make_float4(xv.x * dv.x, xv.y * dv.y, xv.z * dv.z, xv.w * dv.w);
    }
}

// ---------------------------------------------------------------------------
// Fallback (only if ws_size < 2 MiB): fused kernel reading the diagonal of R
// directly.  The 2 MiB of touched diagonal lines are L2-resident after the
// first (b,h) pass, so this is still ~HBM-bound.
// ---------------------------------------------------------------------------
__global__ void rope_scale_fused_kernel(const float4* __restrict__ x,
                                        const float* __restrict__ R,
                                        float4* __restrict__ out, int n4) {
    int i = blockIdx.x * blockDim.x + threadIdx.x;
    if (i < n4) {
        int r  = i & (ROW4 - 1);     // float4 index within one (s,d) plane
        int s  = r >> 5;             // DK/4 = 32 float4 per row
        int d0 = (r & 31) * 4;       // first of 4 consecutive d
        float4 xv = x[i];
        float4 dv;
        dv.x = R[(size_t)((d0 + 0) * DK + (d0 + 0)) * SEQ + s];
        dv.y = R[(size_t)((d0 + 1) * DK + (d0 + 1)) * SEQ + s];
        dv.z = R[(size_t)((d0 + 2) * DK + (d0 + 2)) * SEQ + s];
        dv.w = R[(size_t)((d0 + 3) * DK + (d0 + 3)) * SEQ + s];
        out[i] = make_float4(xv.x * dv.x, xv.y * dv.y, xv.z * dv.z, xv.w * dv.w);
    }
}

extern "C" void kernel_launch(void* const* d_in, const int* in_sizes, int n_in,
                              void* d_out, int out_size, void* d_ws, size_t ws_size,
                              hipStream_t stream) {
    const float* x = (const float*)d_in[0];
    // d_in[1] = token_positions — unused by the reference.
    const float* R = (const float*)d_in[2];
    float* out = (float*)d_out;

    const int n  = out_size;        // 8*16*4096*128 = 67,108,864
    const int n4 = n / 4;           // 16,777,216 float4 elements

    const size_t diag_bytes = (size_t)ROW * sizeof(float);   // 2 MiB

    if (ws_size >= diag_bytes) {
        float* diagT = (float*)d_ws;
        extract_diag_kernel<<<(ROW + 255) / 256, 256, 0, stream>>>(R, diagT);
        rope_scale_kernel<<<(n4 + 255) / 256, 256, 0, stream>>>(
            (const float4*)x, (const float4*)diagT, (float4*)out, n4);
    } else {
        rope_scale_fused_kernel<<<(n4 + 255) / 256, 256, 0, stream>>>(
            (const float4*)x, R, (float4*)out, n4);
    }
}